// Round 1
// baseline (76.293 us; speedup 1.0000x reference)
//
#include <hip/hip_runtime.h>
#include <math.h>

// S4D kernel generation: K[h,l] = 2*Re( sum_n Ck[h,n] * exp(dtA[h,n]*l) )
// H=1024, N2=32, L=4096. Output (H,L) fp32.
//
// Single fused kernel, one block per h, 256 threads, t -> (a=t>>4, b=t&15),
// l = 256*j + 16*a + b.
//   Step 1 (lanes 0-31):  fp64 discretization per mode n: w=exp(dtA),
//          Ck=2*Cc*(w-1)/A, w^16/w^256 by squaring; -> LDS (f32).
//   Step 2 (lanes 0-63):  P[a][n]=(w^16)^a, Q[b][n]=Ck*w^b tables in LDS
//          (transposed: writes 32-consecutive, reads broadcast).
//   Step 3 (all): modes in PAIRS with packed-f32 math (v_pk_fma_f32 etc.):
//          B[n] = P[a][n]*Q[b][n];  s_j = Re(B*W^j), W=w^256, via the real
//          recurrence s_j = p*s_{j-1} - q*s_{j-2} run on packed pairs:
//          3 VOP3P insts per (pair,j) = 1.5 VALU/mode/j. Packed acc2[16],
//          horizontal add only at the end. W-table holds (Wr,Wi,p,-q) so the
//          chain needs no negations. No transcendentals/fp64/spills in hot
//          path (R4 lesson: all indices compile-time constant).
//
// R5 change (this round): pad P/Q row stride 16 -> 17 float4.
//   Old layout: Q read addr = b*256B + np*16B -> bank (np*4)%32 for ALL b
//   => 16-way bank conflict on every Q ds_read_b128 (5.69x, m136), 4-way on P.
//   Stride 17 spreads b over 8 bank-groups: Q 2-way (free), P conflict-free.

#define N2 32
#define L_LEN 4096
#define NTHREADS 256
#define PQS4 17            // padded row stride in float4 units
#define PQS2 34            // same stride in float2 units

__device__ __forceinline__ float2 pk_fma(float2 a, float2 b, float2 c) {
  float2 d;
  asm("v_pk_fma_f32 %0, %1, %2, %3" : "=v"(d) : "v"(a), "v"(b), "v"(c));
  return d;
}
__device__ __forceinline__ float2 pk_mul(float2 a, float2 b) {
  float2 d;
  asm("v_pk_mul_f32 %0, %1, %2" : "=v"(d) : "v"(a), "v"(b));
  return d;
}
__device__ __forceinline__ float2 pk_add(float2 a, float2 b) {
  float2 d;
  asm("v_pk_add_f32 %0, %1, %2" : "=v"(d) : "v"(a), "v"(b));
  return d;
}

__global__ __launch_bounds__(NTHREADS, 4) void s4d_fused_kernel(
    const float* __restrict__ log_dt,      // (H,)
    const float* __restrict__ Cri,         // (H, N2, 2)
    const float* __restrict__ log_A_real,  // (H, N2)
    const float* __restrict__ A_imag,      // (H, N2)
    float* __restrict__ out)               // (H, L)
{
  const int h = blockIdx.x;
  const int t = threadIdx.x;
  const int a = t >> 4;
  const int b = t & 15;

  __shared__ float2 s_w[N2], s_w16[N2], s_ck[N2];
  __shared__ float4 s_Wpq[N2];          // (Wr, Wi, p, -q), W = w^256
  __shared__ float4 s_P[16 * PQS4];     // [a][npair], padded stride 17
  __shared__ float4 s_Q[16 * PQS4];     // [b][npair], padded stride 17

  // ---- Step 1: fp64 prep, one lane per mode ----
  if (t < N2) {
    const int n = t;
    const int idx = h * N2 + n;
    const double dt = exp((double)log_dt[h]);
    const double Ar = -exp((double)log_A_real[idx]);
    const double Ai = (double)A_imag[idx];
    const double xr = dt * Ar;
    const double xi = dt * Ai;
    const double ex = exp(xr);
    const double wr = ex * cos(xi);     // w = exp(dtA)
    const double wi = ex * sin(xi);
    // Ck = 2 * Cc * (w-1)/A  via (w-1)*conj(A)/|A|^2
    const double nr = wr - 1.0, ni = wi;
    const double inv = 1.0 / (Ar * Ar + Ai * Ai);
    const double fr = (nr * Ar + ni * Ai) * inv;
    const double fi = (ni * Ar - nr * Ai) * inv;
    const double c0 = (double)Cri[idx * 2 + 0];
    const double c1 = (double)Cri[idx * 2 + 1];
    s_ck[n] = make_float2((float)(2.0 * (c0 * fr - c1 * fi)),
                          (float)(2.0 * (c0 * fi + c1 * fr)));
    s_w[n] = make_float2((float)wr, (float)wi);
    double ar = wr, ai2 = wi;
#pragma unroll
    for (int k = 0; k < 4; ++k) {       // w^16
      const double tr = ar * ar - ai2 * ai2;
      const double ti = 2.0 * ar * ai2;
      ar = tr; ai2 = ti;
    }
    s_w16[n] = make_float2((float)ar, (float)ai2);
#pragma unroll
    for (int k = 0; k < 4; ++k) {       // w^256
      const double tr = ar * ar - ai2 * ai2;
      const double ti = 2.0 * ar * ai2;
      ar = tr; ai2 = ti;
    }
    s_Wpq[n] = make_float4((float)ar, (float)ai2,
                           (float)(2.0 * ar), (float)(-(ar * ar + ai2 * ai2)));
  }
  __syncthreads();

  // ---- Step 2: P/Q tables (float2 view of the float4 arrays) ----
  if (t < 64) {
    const int n = t & 31;
    if (t < 32) {
      float2* P2 = (float2*)s_P;
      const float2 g = s_w16[n];
      float pr = 1.0f, pi = 0.0f;
#pragma unroll
      for (int aa = 0; aa < 16; ++aa) { // P[aa][n] = (w^16)^aa
        P2[aa * PQS2 + n] = make_float2(pr, pi);
        const float tr = fmaf(pr, g.x, -(pi * g.y));
        const float ti = fmaf(pr, g.y, pi * g.x);
        pr = tr; pi = ti;
      }
    } else {
      float2* Q2 = (float2*)s_Q;
      const float2 w = s_w[n];
      const float2 c = s_ck[n];
      float qr = c.x, qi = c.y;
#pragma unroll
      for (int bb = 0; bb < 16; ++bb) { // Q[bb][n] = Ck * w^bb
        Q2[bb * PQS2 + n] = make_float2(qr, qi);
        const float tr = fmaf(qr, w.x, -(qi * w.y));
        const float ti = fmaf(qr, w.y, qi * w.x);
        qr = tr; qi = ti;
      }
    }
  }
  __syncthreads();

  // ---- Step 3: packed-pair recurrence sweep ----
  float2 acc2[16];
#pragma unroll
  for (int j = 0; j < 16; ++j) acc2[j] = make_float2(0.0f, 0.0f);

  const float4* Pa = s_P + a * PQS4;
  const float4* Qb = s_Q + b * PQS4;

#pragma unroll
  for (int np = 0; np < N2 / 2; ++np) {
    const float4 P = Pa[np];            // (Pr0,Pi0,Pr1,Pi1) broadcast groups
    const float4 Q = Qb[np];
    const float4 W0 = s_Wpq[2 * np];    // uniform broadcast
    const float4 W1 = s_Wpq[2 * np + 1];
    // B = P*Q (complex), per mode of the pair
    const float Br0 = fmaf(P.x, Q.x, -(P.y * Q.y));
    const float Bi0 = fmaf(P.x, Q.y, P.y * Q.x);
    const float Br1 = fmaf(P.z, Q.z, -(P.w * Q.w));
    const float Bi1 = fmaf(P.z, Q.w, P.w * Q.z);
    // s0 = Br, s1 = Re(B*W)
    float2 s0p = make_float2(Br0, Br1);
    float2 s1p = make_float2(fmaf(Br0, W0.x, -(Bi0 * W0.y)),
                             fmaf(Br1, W1.x, -(Bi1 * W1.y)));
    const float2 pp  = make_float2(W0.z, W1.z);
    const float2 mqp = make_float2(W0.w, W1.w);   // -q
    acc2[0] = pk_add(acc2[0], s0p);
    acc2[1] = pk_add(acc2[1], s1p);
#pragma unroll
    for (int j = 2; j < 16; ++j) {
      const float2 s2p = pk_fma(pp, s1p, pk_mul(mqp, s0p));
      acc2[j] = pk_add(acc2[j], s2p);
      s0p = s1p; s1p = s2p;
    }
  }

  float* o = out + (size_t)h * L_LEN + t;  // l = 256*j + t
#pragma unroll
  for (int j = 0; j < 16; ++j) o[j * NTHREADS] = acc2[j].x + acc2[j].y;
}

extern "C" void kernel_launch(void* const* d_in, const int* in_sizes, int n_in,
                              void* d_out, int out_size, void* d_ws, size_t ws_size,
                              hipStream_t stream) {
  const float* log_dt     = (const float*)d_in[0];
  const float* Cri        = (const float*)d_in[1];
  const float* log_A_real = (const float*)d_in[2];
  const float* A_imag     = (const float*)d_in[3];
  float* out = (float*)d_out;
  const int H = in_sizes[0];

  s4d_fused_kernel<<<dim3(H), dim3(NTHREADS), 0, stream>>>(
      log_dt, Cri, log_A_real, A_imag, out);
}

// Round 2
// 74.875 us; speedup vs baseline: 1.0189x; 1.0189x over previous
//
#include <hip/hip_runtime.h>
#include <math.h>

// S4D kernel generation: K[h,l] = 2*Re( sum_n Ck[h,n] * exp(dtA[h,n]*l) )
// H=1024, N2=32, L=4096. Output (H,L) fp32.
//
// One block per h, 256 threads, t -> (a=t>>4, b=t&15), l = 256*j + 16*a + b.
//   Step 1 (lanes 0-31):  fp64 discretization per mode n: w=exp(dtA),
//          Ck=2*Cc*(w-1)/A, w^16/w^256 by squaring; -> LDS (f32).
//   Step 2 (lanes 0-63):  P[a][n]=(w^16)^a, Q[b][n]=Ck*w^b tables in LDS.
//   Step 3 (all): modes in PAIRS; B = P*Q; s_j = Re(B*W^j), W=w^256, via the
//          real recurrence s_j = p*s_{j-1} - q*s_{j-2} on packed pairs.
//
// R5: pad P/Q row stride 16->17 float4 (bank conflicts). -1.1us only ->
//     LDS throughput not critical.
// R6 (this round): planar table packing + pure-compiler packed math.
//   - Tables store pair-planar float4s: P=(Pr0,Pr1,Pi0,Pi1), Q likewise,
//     Wri=(Wr0,Wr1,Wi0,Wi1), Wpq=(p0,p1,-q0,-q1): every packed operand is a
//     contiguous half of ONE ds_read_b128 -> zero operand-assembly v_movs
//     (old layout needed ~8 movs/pair to build pp/mqp from two loads).
//   - Drop ALL inline asm; use ext_vector float2 + __builtin_elementwise_fma
//     so the backend emits v_pk_fma_f32/v_pk_mul_f32 with folded neg
//     modifiers AND can schedule/interleave the 16 independent chains and
//     hoist ds_reads across pairs (asm was pinning tuples + blocking this).

#define N2 32
#define L_LEN 4096
#define NTHREADS 256
#define PQS4 17            // padded row stride in float4 units

typedef float v2 __attribute__((ext_vector_type(2)));

__device__ __forceinline__ v2 vfma(v2 a, v2 b, v2 c) {
  return __builtin_elementwise_fma(a, b, c);
}

__global__ __launch_bounds__(NTHREADS, 4) void s4d_fused_kernel(
    const float* __restrict__ log_dt,      // (H,)
    const float* __restrict__ Cri,         // (H, N2, 2)
    const float* __restrict__ log_A_real,  // (H, N2)
    const float* __restrict__ A_imag,      // (H, N2)
    float* __restrict__ out)               // (H, L)
{
  const int h = blockIdx.x;
  const int t = threadIdx.x;
  const int a = t >> 4;
  const int b = t & 15;

  __shared__ float2 s_w[N2], s_w16[N2], s_ck[N2];
  __shared__ float4 s_Wri[N2 / 2];      // [np] = (Wr0, Wr1, Wi0, Wi1)
  __shared__ float4 s_Wpq[N2 / 2];      // [np] = (p0, p1, -q0, -q1)
  __shared__ float4 s_P[16 * PQS4];     // [a][np] = (Pr0,Pr1,Pi0,Pi1), pad 17
  __shared__ float4 s_Q[16 * PQS4];     // [b][np] = (Qr0,Qr1,Qi0,Qi1), pad 17

  // ---- Step 1: fp64 prep, one lane per mode ----
  if (t < N2) {
    const int n = t;
    const int idx = h * N2 + n;
    const double dt = exp((double)log_dt[h]);
    const double Ar = -exp((double)log_A_real[idx]);
    const double Ai = (double)A_imag[idx];
    const double xr = dt * Ar;
    const double xi = dt * Ai;
    const double ex = exp(xr);
    const double wr = ex * cos(xi);     // w = exp(dtA)
    const double wi = ex * sin(xi);
    // Ck = 2 * Cc * (w-1)/A  via (w-1)*conj(A)/|A|^2
    const double nr = wr - 1.0, ni = wi;
    const double inv = 1.0 / (Ar * Ar + Ai * Ai);
    const double fr = (nr * Ar + ni * Ai) * inv;
    const double fi = (ni * Ar - nr * Ai) * inv;
    const double c0 = (double)Cri[idx * 2 + 0];
    const double c1 = (double)Cri[idx * 2 + 1];
    s_ck[n] = make_float2((float)(2.0 * (c0 * fr - c1 * fi)),
                          (float)(2.0 * (c0 * fi + c1 * fr)));
    s_w[n] = make_float2((float)wr, (float)wi);
    double ar = wr, ai2 = wi;
#pragma unroll
    for (int k = 0; k < 4; ++k) {       // w^16
      const double tr = ar * ar - ai2 * ai2;
      const double ti = 2.0 * ar * ai2;
      ar = tr; ai2 = ti;
    }
    s_w16[n] = make_float2((float)ar, (float)ai2);
#pragma unroll
    for (int k = 0; k < 4; ++k) {       // w^256
      const double tr = ar * ar - ai2 * ai2;
      const double ti = 2.0 * ar * ai2;
      ar = tr; ai2 = ti;
    }
    // planar per-pair W tables: component (n&1) of pair (n>>1)
    float* Wri_f = (float*)s_Wri;
    float* Wpq_f = (float*)s_Wpq;
    const int pbase = (n >> 1) * 4 + (n & 1);
    Wri_f[pbase + 0] = (float)ar;                        // Wr
    Wri_f[pbase + 2] = (float)ai2;                       // Wi
    Wpq_f[pbase + 0] = (float)(2.0 * ar);                // p
    Wpq_f[pbase + 2] = (float)(-(ar * ar + ai2 * ai2));  // -q
  }
  __syncthreads();

  // ---- Step 2: P/Q tables, planar per-pair writes ----
  if (t < 64) {
    const int n = t & 31;
    const int comp = n & 1;
    const int np = n >> 1;
    if (t < 32) {
      float* Pf = (float*)s_P;
      const float2 g = s_w16[n];
      float pr = 1.0f, pi = 0.0f;
#pragma unroll
      for (int aa = 0; aa < 16; ++aa) { // P[aa][n] = (w^16)^aa
        const int base = (aa * PQS4 + np) * 4 + comp;
        Pf[base + 0] = pr;
        Pf[base + 2] = pi;
        const float tr = fmaf(pr, g.x, -(pi * g.y));
        const float ti = fmaf(pr, g.y, pi * g.x);
        pr = tr; pi = ti;
      }
    } else {
      float* Qf = (float*)s_Q;
      const float2 w = s_w[n];
      const float2 c = s_ck[n];
      float qr = c.x, qi = c.y;
#pragma unroll
      for (int bb = 0; bb < 16; ++bb) { // Q[bb][n] = Ck * w^bb
        const int base = (bb * PQS4 + np) * 4 + comp;
        Qf[base + 0] = qr;
        Qf[base + 2] = qi;
        const float tr = fmaf(qr, w.x, -(qi * w.y));
        const float ti = fmaf(qr, w.y, qi * w.x);
        qr = tr; qi = ti;
      }
    }
  }
  __syncthreads();

  // ---- Step 3: packed-pair recurrence sweep (pure compiler v2 math) ----
  v2 acc[16];
#pragma unroll
  for (int j = 0; j < 16; ++j) acc[j] = (v2){0.0f, 0.0f};

  const float4* Pa = s_P + a * PQS4;
  const float4* Qb = s_Q + b * PQS4;

#pragma unroll
  for (int np = 0; np < N2 / 2; ++np) {
    const float4 P4 = Pa[np];           // (Pr0,Pr1,Pi0,Pi1)
    const float4 Q4 = Qb[np];           // (Qr0,Qr1,Qi0,Qi1)
    const float4 Wri4 = s_Wri[np];      // (Wr0,Wr1,Wi0,Wi1) uniform
    const float4 Wpq4 = s_Wpq[np];      // (p0,p1,-q0,-q1)   uniform
    const v2 Prp = (v2){P4.x, P4.y}, Pip = (v2){P4.z, P4.w};
    const v2 Qrp = (v2){Q4.x, Q4.y}, Qip = (v2){Q4.z, Q4.w};
    const v2 Wrp = (v2){Wri4.x, Wri4.y}, Wip = (v2){Wri4.z, Wri4.w};
    const v2 pp  = (v2){Wpq4.x, Wpq4.y}, mqp = (v2){Wpq4.z, Wpq4.w};

    // B = P*Q (complex, per packed mode)
    const v2 Brp = vfma(Prp, Qrp, -(Pip * Qip));
    const v2 Bip = vfma(Prp, Qip, Pip * Qrp);
    // s0 = Re(B), s1 = Re(B*W)
    v2 s0 = Brp;
    v2 s1 = vfma(Brp, Wrp, -(Bip * Wip));
    acc[0] += s0;
    acc[1] += s1;
#pragma unroll
    for (int j = 2; j < 16; ++j) {
      const v2 s2 = vfma(pp, s1, mqp * s0);
      acc[j] += s2;
      s0 = s1; s1 = s2;
    }
  }

  float* o = out + (size_t)h * L_LEN + t;  // l = 256*j + t
#pragma unroll
  for (int j = 0; j < 16; ++j) o[j * NTHREADS] = acc[j].x + acc[j].y;
}

extern "C" void kernel_launch(void* const* d_in, const int* in_sizes, int n_in,
                              void* d_out, int out_size, void* d_ws, size_t ws_size,
                              hipStream_t stream) {
  const float* log_dt     = (const float*)d_in[0];
  const float* Cri        = (const float*)d_in[1];
  const float* log_A_real = (const float*)d_in[2];
  const float* A_imag     = (const float*)d_in[3];
  float* out = (float*)d_out;
  const int H = in_sizes[0];

  s4d_fused_kernel<<<dim3(H), dim3(NTHREADS), 0, stream>>>(
      log_dt, Cri, log_A_real, A_imag, out);
}